// Round 1
// 704.601 us; speedup vs baseline: 1.1348x; 1.1348x over previous
//
#include <hip/hip_runtime.h>
#include <cmath>

#define B_ 32
#define N_ 64
#define H_ 256
#define G3_ 768           // 3*H
#define INTER_ 912        // 2H + 6C + C1
#define KP_ 928           // INTER_ padded to 29*32 for bf16 MFMA GEMM
#define FCIN_ 2992        // 3*INTER + H

#define PADA 264          // hA row stride (bf16 elems)
#define PADX 72           // xA row stride (bf16 elems)

typedef __attribute__((ext_vector_type(8))) short short8;
typedef __attribute__((ext_vector_type(4))) short sshort4;
typedef __attribute__((ext_vector_type(4))) float float4v;

#define MFMA __builtin_amdgcn_mfma_f32_16x16x32_bf16

// single-instruction transcendentals: v_exp_f32 is exp2, v_rcp_f32
__device__ __forceinline__ float sigmoid_f(float x) {
    return __builtin_amdgcn_rcpf(1.0f + __builtin_amdgcn_exp2f(-1.44269504f * x));
}
__device__ __forceinline__ float tanh_fast(float x) {
    // tanh(x) = 1 - 2/(1+e^{2x}); exp2(+-inf) saturates correctly -> no clamp
    return 1.0f - 2.0f * __builtin_amdgcn_rcpf(1.0f + __builtin_amdgcn_exp2f(2.88539008f * x));
}
__device__ __forceinline__ unsigned f2bf_bits(float x) {
    unsigned u = __float_as_uint(x);
    return (u + 0x7fffu + ((u >> 16) & 1u)) >> 16;
}
__device__ __forceinline__ short f2bf(float x) { return (short)f2bf_bits(x); }

// ---------------------------------------------------------------------------
// prep: (a) Bfrag   = gru2d weights, fragment-major bf16 (layout verified R2)
//       (b) Bfrag1  = gru1d Whh, same pack (8 kt)
//       (c) Bfrag1W = gru1d Wih (768 x 912), same pack, K zero-padded to 928
//       (d) fc1Wt transpose
// Fragment layout: [kt][ntile(48)][lane(64)][j(8)] bf16; value = W[n][k] with
// n = ntile*16 + (lane&15), k = kt*32 + (lane>>4)*8 + j.
// ---------------------------------------------------------------------------
__global__ __launch_bounds__(256) void prep_kernel(
        const float* __restrict__ Whh2, const float* __restrict__ Wih2,
        const float* __restrict__ Whh1, const float* __restrict__ Wih1,
        const float* __restrict__ fc1W,
        short* __restrict__ Bfrag, short* __restrict__ Bfrag1,
        short* __restrict__ Bfrag1W, float* __restrict__ fc1Wt) {
    int idx = blockIdx.x * 256 + threadIdx.x;
    if (idx < 10 * 48 * 64 * 8) {
        int j = idx & 7, lane = (idx >> 3) & 63, tile = idx >> 9;
        int nt = tile % 48, kt = tile / 48;
        int n = nt * 16 + (lane & 15);
        int kb = (lane >> 4) * 8 + j;
        float v = (kt < 8) ? Whh2[n * 256 + kt * 32 + kb]
                           : Wih2[n * 64 + (kt - 8) * 32 + kb];
        Bfrag[idx] = f2bf(v);
    }
    if (idx < 8 * 48 * 64 * 8) {
        int j = idx & 7, lane = (idx >> 3) & 63, tile = idx >> 9;
        int nt = tile % 48, kt = tile / 48;
        int n = nt * 16 + (lane & 15);
        int k = kt * 32 + (lane >> 4) * 8 + j;
        Bfrag1[idx] = f2bf(Whh1[n * 256 + k]);
    }
    if (idx < 29 * 48 * 64 * 8) {
        int j = idx & 7, lane = (idx >> 3) & 63, tile = idx >> 9;
        int nt = tile % 48, kt = tile / 48;
        int n = nt * 16 + (lane & 15);
        int k = kt * 32 + (lane >> 4) * 8 + j;
        Bfrag1W[idx] = (k < INTER_) ? f2bf(Wih1[n * INTER_ + k]) : (short)0;
    }
    if (idx < FCIN_ * 256) {
        int o = idx & 255, i = idx >> 8;
        fc1Wt[idx] = fc1W[o * FCIN_ + i];
    }
}

// ---------------------------------------------------------------------------
// reduce_states: d[] reductions + x1 copy -> f[:, 0:400]
// ---------------------------------------------------------------------------
__global__ __launch_bounds__(256) void reduce_states_kernel(
        const float* __restrict__ states, const float* __restrict__ x1,
        float* __restrict__ f) {
    const int c = threadIdx.x & 63;
    const int bj = blockIdx.x * 4 + (threadIdx.x >> 6);
    const int b = bj >> 6, j = bj & 63;
    const float* p1 = states + b * 262144 + j * 64 + c;
    const float* p2 = states + b * 262144 + j * 4096 + c;
    float mx1 = -1e30f, mn1 = 1e30f, sm1 = 0.f;
    float mx2 = -1e30f, mn2 = 1e30f, sm2 = 0.f;
    #pragma unroll 8
    for (int n = 0; n < 64; ++n) {
        float v = p1[n * 4096];
        mx1 = fmaxf(mx1, v); mn1 = fminf(mn1, v); sm1 += v;
    }
    #pragma unroll 8
    for (int m = 0; m < 64; ++m) {
        float v = p2[m * 64];
        mx2 = fmaxf(mx2, v); mn2 = fminf(mn2, v); sm2 += v;
    }
    float* fr = f + bj * INTER_;
    fr[16 + c]  = mx1;  fr[80 + c]  = sm1 * (1.f / 64.f);  fr[144 + c] = mn1;
    fr[208 + c] = mx2;  fr[272 + c] = sm2 * (1.f / 64.f);  fr[336 + c] = mn2;
    if (c < 16) fr[c] = x1[bj * 16 + c];
}

// ---------------------------------------------------------------------------
// gru2d via MFMA bf16, B-resident. R4 restructure:
//  - MFMA chains grouped by gate (R -> N -> Z) so gate VALU (sigmoid/tanh)
//    issues while later MFMA groups occupy the matrix pipe.
//  - hA double-buffered -> single __syncthreads per timestep.
//  - biases folded into accumulator init; exp2/rcp intrinsics.
// ---------------------------------------------------------------------------
__global__ __launch_bounds__(512, 2) void gru2d_mfma(
        const float* __restrict__ states,
        const int* __restrict__ perm1, const int* __restrict__ perm2,
        const short* __restrict__ Bfrag,
        const float* __restrict__ bih, const float* __restrict__ bhh,
        float* __restrict__ f) {
    __shared__ short hA[2][16 * PADA];
    __shared__ short xA[2][16 * PADX];
    __shared__ short8 Blds[2 * 48 * 64];
    __shared__ int perms[1024];

    const int tid = threadIdx.x;
    const int lane = tid & 63;
    const int w = tid >> 6;
    const int m = lane & 15;
    const int q = lane >> 4;
    const bool sd2 = blockIdx.x >= 128;
    const int sblock = (blockIdx.x & 127) * 16;

    for (int i = tid; i < 1024; i += 512) {
        int r = i >> 6, t = i & 63;
        int qq = (sblock + r) & 63;
        perms[i] = sd2 ? perm2[qq * 64 + t] : perm1[qq * 64 + t];
    }
    for (int i = tid; i < 16 * PADA; i += 512) hA[0][i] = 0;
    {
        const uint4* src = (const uint4*)(Bfrag + 6 * 48 * 64 * 8);
        uint4* dst = (uint4*)Blds;
        #pragma unroll
        for (int rep = 0; rep < 12; ++rep)
            dst[tid + rep * 512] = src[tid + rep * 512];
    }

    const short8* Bf8 = (const short8*)Bfrag;
    short8 Bres[36];
    #pragma unroll
    for (int kt = 0; kt < 6; ++kt)
        #pragma unroll
        for (int j = 0; j < 6; ++j)
            Bres[kt * 6 + j] = Bf8[(kt * 48 + 8 * j + w) * 64 + lane];

    const int u0 = 16 * w + m;
    const int u1 = 128 + u0;
    const float br0 = bih[u0] + bhh[u0],             br1 = bih[u1] + bhh[u1];
    const float bz0 = bih[256 + u0] + bhh[256 + u0], bz1 = bih[256 + u1] + bhh[256 + u1];
    const float bnx0 = bih[512 + u0], bnx1 = bih[512 + u1];
    const float bnh0 = bhh[512 + u0], bnh1 = bhh[512 + u1];

    float4v hreg0 = {0.f, 0.f, 0.f, 0.f}, hreg1 = {0.f, 0.f, 0.f, 0.f};

    {
        #pragma unroll
        for (int half = 0; half < 2; ++half) {
            int i = tid + half * 512;
            int r = i >> 6, c = i & 63;
            int s = sblock + r, b = s >> 6, qq = s & 63;
            int p = perms[r * 64 + 0];
            int src = sd2 ? ((b * 64 + p) * 64 + qq) * 64 + c
                          : ((b * 64 + qq) * 64 + p) * 64 + c;
            xA[0][r * PADX + c] = f2bf(states[src]);
        }
    }
    __syncthreads();

    for (int t = 0; t < 64; ++t) {
        const short* hAc = hA[t & 1];
        const short* xAc = xA[t & 1];

        short8 Bx[12];
        #pragma unroll
        for (int kt = 0; kt < 2; ++kt)
            #pragma unroll
            for (int j = 0; j < 6; ++j)
                Bx[kt * 6 + j] = Bf8[((8 + kt) * 48 + 8 * j + w) * 64 + lane];

        float xg0 = 0.f, xg1 = 0.f;
        int w0 = -1, w1 = -1;
        if (t + 1 < 64) {
            #pragma unroll
            for (int half = 0; half < 2; ++half) {
                int i = tid + half * 512;
                int r = i >> 6, c = i & 63;
                int s = sblock + r, b = s >> 6, qq = s & 63;
                int p = perms[r * 64 + t + 1];
                int src = sd2 ? ((b * 64 + p) * 64 + qq) * 64 + c
                              : ((b * 64 + qq) * 64 + p) * 64 + c;
                float v = states[src];
                if (half == 0) { xg0 = v; w0 = r * PADX + c; }
                else           { xg1 = v; w1 = r * PADX + c; }
            }
        }

        short8 ax0 = *(const short8*)(xAc + m * PADX + 0 * 32 + q * 8);
        short8 ax1 = *(const short8*)(xAc + m * PADX + 1 * 32 + q * 8);

        // ---- R group ----
        float4v aR0 = {br0, br0, br0, br0}, aR1 = {br1, br1, br1, br1};
        #pragma unroll
        for (int kt = 0; kt < 6; ++kt) {
            short8 a = *(const short8*)(hAc + m * PADA + kt * 32 + q * 8);
            aR0 = MFMA(a, Bres[kt * 6 + 0], aR0, 0, 0, 0);
            aR1 = MFMA(a, Bres[kt * 6 + 1], aR1, 0, 0, 0);
        }
        #pragma unroll
        for (int kt = 0; kt < 2; ++kt) {
            short8 a = *(const short8*)(hAc + m * PADA + (6 + kt) * 32 + q * 8);
            aR0 = MFMA(a, Blds[(kt * 48 + 0 + w) * 64 + lane], aR0, 0, 0, 0);
            aR1 = MFMA(a, Blds[(kt * 48 + 8 + w) * 64 + lane], aR1, 0, 0, 0);
        }
        aR0 = MFMA(ax0, Bx[0], aR0, 0, 0, 0);
        aR1 = MFMA(ax0, Bx[1], aR1, 0, 0, 0);
        aR0 = MFMA(ax1, Bx[6], aR0, 0, 0, 0);
        aR1 = MFMA(ax1, Bx[7], aR1, 0, 0, 0);
        float r0[4], r1[4];
        #pragma unroll
        for (int p = 0; p < 4; ++p) {
            r0[p] = sigmoid_f(aR0[p]);
            r1[p] = sigmoid_f(aR1[p]);
        }

        // ---- N group (hides r-sigmoids under issue) ----
        float4v aNh0 = {bnh0, bnh0, bnh0, bnh0}, aNh1 = {bnh1, bnh1, bnh1, bnh1};
        float4v aNx0 = {bnx0, bnx0, bnx0, bnx0}, aNx1 = {bnx1, bnx1, bnx1, bnx1};
        #pragma unroll
        for (int kt = 0; kt < 6; ++kt) {
            short8 a = *(const short8*)(hAc + m * PADA + kt * 32 + q * 8);
            aNh0 = MFMA(a, Bres[kt * 6 + 4], aNh0, 0, 0, 0);
            aNh1 = MFMA(a, Bres[kt * 6 + 5], aNh1, 0, 0, 0);
        }
        #pragma unroll
        for (int kt = 0; kt < 2; ++kt) {
            short8 a = *(const short8*)(hAc + m * PADA + (6 + kt) * 32 + q * 8);
            aNh0 = MFMA(a, Blds[(kt * 48 + 32 + w) * 64 + lane], aNh0, 0, 0, 0);
            aNh1 = MFMA(a, Blds[(kt * 48 + 40 + w) * 64 + lane], aNh1, 0, 0, 0);
        }
        aNx0 = MFMA(ax0, Bx[4], aNx0, 0, 0, 0);
        aNx1 = MFMA(ax0, Bx[5], aNx1, 0, 0, 0);
        aNx0 = MFMA(ax1, Bx[10], aNx0, 0, 0, 0);
        aNx1 = MFMA(ax1, Bx[11], aNx1, 0, 0, 0);
        float n0[4], n1[4];
        #pragma unroll
        for (int p = 0; p < 4; ++p) {
            n0[p] = tanh_fast(aNx0[p] + r0[p] * aNh0[p]);
            n1[p] = tanh_fast(aNx1[p] + r1[p] * aNh1[p]);
        }

        // ---- Z group (hides tanh under issue) ----
        float4v aZ0 = {bz0, bz0, bz0, bz0}, aZ1 = {bz1, bz1, bz1, bz1};
        #pragma unroll
        for (int kt = 0; kt < 6; ++kt) {
            short8 a = *(const short8*)(hAc + m * PADA + kt * 32 + q * 8);
            aZ0 = MFMA(a, Bres[kt * 6 + 2], aZ0, 0, 0, 0);
            aZ1 = MFMA(a, Bres[kt * 6 + 3], aZ1, 0, 0, 0);
        }
        #pragma unroll
        for (int kt = 0; kt < 2; ++kt) {
            short8 a = *(const short8*)(hAc + m * PADA + (6 + kt) * 32 + q * 8);
            aZ0 = MFMA(a, Blds[(kt * 48 + 16 + w) * 64 + lane], aZ0, 0, 0, 0);
            aZ1 = MFMA(a, Blds[(kt * 48 + 24 + w) * 64 + lane], aZ1, 0, 0, 0);
        }
        aZ0 = MFMA(ax0, Bx[2], aZ0, 0, 0, 0);
        aZ1 = MFMA(ax0, Bx[3], aZ1, 0, 0, 0);
        aZ0 = MFMA(ax1, Bx[8], aZ0, 0, 0, 0);
        aZ1 = MFMA(ax1, Bx[9], aZ1, 0, 0, 0);

        short* hAn = hA[(t + 1) & 1];
        #pragma unroll
        for (int p = 0; p < 4; ++p) {
            int row = q * 4 + p;
            float z0 = sigmoid_f(aZ0[p]);
            float h0 = n0[p] + z0 * (hreg0[p] - n0[p]);
            hreg0[p] = h0;
            hAn[row * PADA + u0] = f2bf(h0);
            float z1 = sigmoid_f(aZ1[p]);
            float h1 = n1[p] + z1 * (hreg1[p] - n1[p]);
            hreg1[p] = h1;
            hAn[row * PADA + u1] = f2bf(h1);
        }
        if (t + 1 < 64) {
            xA[(t + 1) & 1][w0] = f2bf(xg0);
            xA[(t + 1) & 1][w1] = f2bf(xg1);
        }
        __syncthreads();
    }

    const int off = sd2 ? 656 : 400;
    #pragma unroll
    for (int p = 0; p < 4; ++p) {
        int s = sblock + q * 4 + p;
        f[s * INTER_ + off + u0] = hreg0[p];
        f[s * INTER_ + off + u1] = hreg1[p];
    }
}

// ---------------------------------------------------------------------------
// convert f (fp32 [2048][912]) -> fbf (bf16 [2048][928], zero-padded K)
// ---------------------------------------------------------------------------
__global__ __launch_bounds__(256) void convert_f_kernel(
        const float* __restrict__ f, short* __restrict__ fbf) {
    int idx = blockIdx.x * 256 + threadIdx.x;
    int row = idx / 232;
    int c4 = (idx - row * 232) * 4;
    if (row >= 2048) return;
    sshort4 o;
    if (c4 < INTER_) {
        float4v v = *(const float4v*)(f + row * INTER_ + c4);
        o[0] = f2bf(v[0]); o[1] = f2bf(v[1]); o[2] = f2bf(v[2]); o[3] = f2bf(v[3]);
    } else {
        o[0] = 0; o[1] = 0; o[2] = 0; o[3] = 0;
    }
    *(sshort4*)(fbf + row * KP_ + c4) = o;
}

// ---------------------------------------------------------------------------
// xw1[2048][768] = fbf[2048][928] @ Wih1^T (+bih1), bf16 MFMA.
// grid (12 n-blocks, 32 m-blocks) x 256 thr (4 waves); wave w -> rows w*16..+15,
// 4 n-subtiles of 16; reg double-buffered K loop (29 kt), no LDS.
// ---------------------------------------------------------------------------
__global__ __launch_bounds__(256) void gemm_xw1_mfma(
        const short* __restrict__ fbf, const short* __restrict__ BfragW,
        const float* __restrict__ bih, float* __restrict__ xw) {
    const int tid = threadIdx.x;
    const int lane = tid & 63;
    const int w = tid >> 6;
    const int m = lane & 15;
    const int q = lane >> 4;
    const int tn = blockIdx.x;
    const int tm = blockIdx.y;
    const int rowb = tm * 64 + w * 16;
    const short8* Bf8 = (const short8*)BfragW;

    float4v acc[4];
    #pragma unroll
    for (int nn = 0; nn < 4; ++nn) {
        float b = bih[tn * 64 + nn * 16 + m];
        acc[nn][0] = b; acc[nn][1] = b; acc[nn][2] = b; acc[nn][3] = b;
    }

    const short* arow = fbf + (rowb + m) * KP_;
    short8 a_cur = *(const short8*)(arow + q * 8);
    short8 b_cur[4];
    #pragma unroll
    for (int nn = 0; nn < 4; ++nn)
        b_cur[nn] = Bf8[(tn * 4 + nn) * 64 + lane];

    for (int kt = 0; kt < 29; ++kt) {
        short8 a_nxt = a_cur;
        short8 b_nxt[4];
        if (kt + 1 < 29) {
            a_nxt = *(const short8*)(arow + (kt + 1) * 32 + q * 8);
            #pragma unroll
            for (int nn = 0; nn < 4; ++nn)
                b_nxt[nn] = Bf8[((kt + 1) * 48 + tn * 4 + nn) * 64 + lane];
        }
        #pragma unroll
        for (int nn = 0; nn < 4; ++nn)
            acc[nn] = MFMA(a_cur, b_cur[nn], acc[nn], 0, 0, 0);
        a_cur = a_nxt;
        #pragma unroll
        for (int nn = 0; nn < 4; ++nn) b_cur[nn] = b_nxt[nn];
    }

    #pragma unroll
    for (int p = 0; p < 4; ++p) {
        int row = rowb + q * 4 + p;
        #pragma unroll
        for (int nn = 0; nn < 4; ++nn)
            xw[row * G3_ + tn * 64 + nn * 16 + m] = acc[nn][p];
    }
}

// ---------------------------------------------------------------------------
// gru1d via MFMA bf16. Same R4 restructure as gru2d: gate-grouped MFMA
// chains, hA double-buffer + single barrier, bias-folded init.
// ---------------------------------------------------------------------------
__global__ __launch_bounds__(512, 2) void gru1d_mfma(
        const float* __restrict__ xw, const short* __restrict__ Bfrag1,
        const float* __restrict__ bhh, float* __restrict__ hlast) {
    __shared__ short hA[2][16 * PADA];
    __shared__ short8 Blds[2 * 48 * 64];   // kt 6,7

    const int tid = threadIdx.x;
    const int lane = tid & 63;
    const int w = tid >> 6;
    const int m = lane & 15;
    const int q = lane >> 4;
    const int sblock = blockIdx.x * 16;

    for (int i = tid; i < 16 * PADA; i += 512) hA[0][i] = 0;
    {
        const uint4* src = (const uint4*)(Bfrag1 + 6 * 48 * 64 * 8);
        uint4* dst = (uint4*)Blds;
        #pragma unroll
        for (int rep = 0; rep < 12; ++rep)
            dst[tid + rep * 512] = src[tid + rep * 512];
    }
    const short8* Bf8 = (const short8*)Bfrag1;
    short8 Bres[36];
    #pragma unroll
    for (int kt = 0; kt < 6; ++kt)
        #pragma unroll
        for (int j = 0; j < 6; ++j)
            Bres[kt * 6 + j] = Bf8[(kt * 48 + 8 * j + w) * 64 + lane];

    const int u0 = 16 * w + m;
    const int u1 = 128 + u0;
    const float br0 = bhh[u0],       br1 = bhh[u1];
    const float bz0 = bhh[256 + u0], bz1 = bhh[256 + u1];
    const float bn0 = bhh[512 + u0], bn1 = bhh[512 + u1];

    float4v hreg0 = {0.f, 0.f, 0.f, 0.f}, hreg1 = {0.f, 0.f, 0.f, 0.f};
    __syncthreads();

    for (int t = 0; t < 64; ++t) {
        const short* hAc = hA[t & 1];

        float giR0[4], giR1[4], giZ0[4], giZ1[4], giN0[4], giN1[4];
        #pragma unroll
        for (int p = 0; p < 4; ++p) {
            const float* gr = xw + ((sblock + q * 4 + p) * 64 + t) * G3_;
            giR0[p] = gr[u0];        giR1[p] = gr[u1];
            giZ0[p] = gr[256 + u0];  giZ1[p] = gr[256 + u1];
            giN0[p] = gr[512 + u0];  giN1[p] = gr[512 + u1];
        }

        // ---- R group ----
        float4v aR0 = {br0, br0, br0, br0}, aR1 = {br1, br1, br1, br1};
        #pragma unroll
        for (int kt = 0; kt < 6; ++kt) {
            short8 a = *(const short8*)(hAc + m * PADA + kt * 32 + q * 8);
            aR0 = MFMA(a, Bres[kt * 6 + 0], aR0, 0, 0, 0);
            aR1 = MFMA(a, Bres[kt * 6 + 1], aR1, 0, 0, 0);
        }
        #pragma unroll
        for (int kt = 0; kt < 2; ++kt) {
            short8 a = *(const short8*)(hAc + m * PADA + (6 + kt) * 32 + q * 8);
            aR0 = MFMA(a, Blds[(kt * 48 + 0 + w) * 64 + lane], aR0, 0, 0, 0);
            aR1 = MFMA(a, Blds[(kt * 48 + 8 + w) * 64 + lane], aR1, 0, 0, 0);
        }
        float r0[4], r1[4];
        #pragma unroll
        for (int p = 0; p < 4; ++p) {
            r0[p] = sigmoid_f(giR0[p] + aR0[p]);
            r1[p] = sigmoid_f(giR1[p] + aR1[p]);
        }

        // ---- N group ----
        float4v aN0 = {bn0, bn0, bn0, bn0}, aN1 = {bn1, bn1, bn1, bn1};
        #pragma unroll
        for (int kt = 0; kt < 6; ++kt) {
            short8 a = *(const short8*)(hAc + m * PADA + kt * 32 + q * 8);
            aN0 = MFMA(a, Bres[kt * 6 + 4], aN0, 0, 0, 0);
            aN1 = MFMA(a, Bres[kt * 6 + 5], aN1, 0, 0, 0);
        }
        #pragma unroll
        for (int kt = 0; kt < 2; ++kt) {
            short8 a = *(const short8*)(hAc + m * PADA + (6 + kt) * 32 + q * 8);
            aN0 = MFMA(a, Blds[(kt * 48 + 32 + w) * 64 + lane], aN0, 0, 0, 0);
            aN1 = MFMA(a, Blds[(kt * 48 + 40 + w) * 64 + lane], aN1, 0, 0, 0);
        }
        float n0[4], n1[4];
        #pragma unroll
        for (int p = 0; p < 4; ++p) {
            n0[p] = tanh_fast(giN0[p] + r0[p] * aN0[p]);
            n1[p] = tanh_fast(giN1[p] + r1[p] * aN1[p]);
        }

        // ---- Z group ----
        float4v aZ0 = {bz0, bz0, bz0, bz0}, aZ1 = {bz1, bz1, bz1, bz1};
        #pragma unroll
        for (int kt = 0; kt < 6; ++kt) {
            short8 a = *(const short8*)(hAc + m * PADA + kt * 32 + q * 8);
            aZ0 = MFMA(a, Bres[kt * 6 + 2], aZ0, 0, 0, 0);
            aZ1 = MFMA(a, Bres[kt * 6 + 3], aZ1, 0, 0, 0);
        }
        #pragma unroll
        for (int kt = 0; kt < 2; ++kt) {
            short8 a = *(const short8*)(hAc + m * PADA + (6 + kt) * 32 + q * 8);
            aZ0 = MFMA(a, Blds[(kt * 48 + 16 + w) * 64 + lane], aZ0, 0, 0, 0);
            aZ1 = MFMA(a, Blds[(kt * 48 + 24 + w) * 64 + lane], aZ1, 0, 0, 0);
        }

        short* hAn = hA[(t + 1) & 1];
        #pragma unroll
        for (int p = 0; p < 4; ++p) {
            int row = q * 4 + p;
            float z0 = sigmoid_f(giZ0[p] + aZ0[p]);
            float h0 = n0[p] + z0 * (hreg0[p] - n0[p]);
            hreg0[p] = h0;
            hAn[row * PADA + u0] = f2bf(h0);
            float z1 = sigmoid_f(giZ1[p] + aZ1[p]);
            float h1 = n1[p] + z1 * (hreg1[p] - n1[p]);
            hreg1[p] = h1;
            hAn[row * PADA + u1] = f2bf(h1);
        }
        __syncthreads();
    }

    #pragma unroll
    for (int p = 0; p < 4; ++p) {
        int s = sblock + q * 4 + p;
        hlast[s * 256 + u0] = hreg0[p];
        hlast[s * 256 + u1] = hreg1[p];
    }
}

// ---------------------------------------------------------------------------
// tail: g = [f.max(1)|f.mean(1)|f.min(1)|hlast], fc1+relu, fc2
// ---------------------------------------------------------------------------
__global__ __launch_bounds__(256) void tail_kernel(
        const float* __restrict__ f, const float* __restrict__ hlast,
        const float* __restrict__ fc1Wt, const float* __restrict__ fc1b,
        const float* __restrict__ fc2W, const float* __restrict__ fc2b,
        float* __restrict__ out) {
    __shared__ float g_lds[FCIN_];
    __shared__ float red[256];
    const int tid = threadIdx.x;
    const int b = blockIdx.x;
    for (int i = tid; i < INTER_; i += 256) {
        float mx = -1e30f, mn = 1e30f, sm = 0.f;
        for (int t = 0; t < 64; ++t) {
            float v = f[(b * 64 + t) * INTER_ + i];
            mx = fmaxf(mx, v); mn = fminf(mn, v); sm += v;
        }
        g_lds[i] = mx;
        g_lds[INTER_ + i] = sm * (1.f / 64.f);
        g_lds[2 * INTER_ + i] = mn;
    }
    g_lds[3 * INTER_ + tid] = hlast[b * 256 + tid];
    __syncthreads();
    float acc = fc1b[tid];
    for (int i = 0; i < FCIN_; ++i)
        acc = fmaf(g_lds[i], fc1Wt[i * 256 + tid], acc);
    float hv = fmaxf(acc, 0.f);
    red[tid] = hv * fc2W[tid];
    __syncthreads();
    if (tid == 0) {
        float s = fc2b[0];
        for (int i = 0; i < 256; ++i) s += red[i];
        out[b] = s;
    }
}

// ---------------------------------------------------------------------------
extern "C" void kernel_launch(void* const* d_in, const int* in_sizes, int n_in,
                              void* d_out, int out_size, void* d_ws, size_t ws_size,
                              hipStream_t stream) {
    const float* x1     = (const float*)d_in[0];
    const float* states = (const float*)d_in[1];
    const int*   perm1  = (const int*)d_in[2];
    const int*   perm2  = (const int*)d_in[3];
    const float* Wih2   = (const float*)d_in[4];
    const float* Whh2   = (const float*)d_in[5];
    const float* bih2   = (const float*)d_in[6];
    const float* bhh2   = (const float*)d_in[7];
    const float* Wih1   = (const float*)d_in[8];
    const float* Whh1   = (const float*)d_in[9];
    const float* bih1   = (const float*)d_in[10];
    const float* bhh1   = (const float*)d_in[11];
    const float* fc1W   = (const float*)d_in[12];
    const float* fc1b   = (const float*)d_in[13];
    const float* fc2W   = (const float*)d_in[14];
    const float* fc2b   = (const float*)d_in[15];
    float* out = (float*)d_out;

    float* ws = (float*)d_ws;
    short* Bfrag   = (short*)ws;                          // 245760 bf16
    short* Bfrag1  = (short*)(ws + 122880);               // 196608 bf16
    short* Bfrag1W = (short*)(ws + 122880 + 98304);       // 712704 bf16
    float* fc1Wt   = ws + 577536;                         // 765952 f
    float* f       = fc1Wt + FCIN_ * 256;                 // 1343488
    short* fbf     = (short*)(f + 2048 * INTER_);         // at 3211264 f; 1900544 bf16
    float* xw1     = f + 2048 * INTER_ + 950272;          // 4161536
    float* hlast   = xw1 + 2048 * G3_;                    // 5734400 (end 5742592 f)

    prep_kernel<<<dim3(2992), 256, 0, stream>>>(Whh2, Wih2, Whh1, Wih1, fc1W,
                                                Bfrag, Bfrag1, Bfrag1W, fc1Wt);
    reduce_states_kernel<<<dim3(512), 256, 0, stream>>>(states, x1, f);
    gru2d_mfma<<<dim3(256), 512, 0, stream>>>(states, perm1, perm2, Bfrag,
                                              bih2, bhh2, f);
    convert_f_kernel<<<dim3(1856), 256, 0, stream>>>(f, fbf);
    gemm_xw1_mfma<<<dim3(12, 32), 256, 0, stream>>>(fbf, Bfrag1W, bih1, xw1);
    gru1d_mfma<<<dim3(2), 512, 0, stream>>>(xw1, Bfrag1, bhh1, hlast);
    tail_kernel<<<dim3(32), 256, 0, stream>>>(f, hlast, fc1Wt, fc1b, fc2W, fc2b, out);
}

// Round 2
// 632.592 us; speedup vs baseline: 1.2640x; 1.1138x over previous
//
#include <hip/hip_runtime.h>
#include <cmath>

#define B_ 32
#define N_ 64
#define H_ 256
#define G3_ 768           // 3*H
#define INTER_ 912        // 2H + 6C + C1
#define KP_ 928           // INTER_ padded to 29*32 for bf16 MFMA GEMM
#define FCIN_ 2992        // 3*INTER + H

#define PADA 264          // hA row stride (bf16 elems)
#define PADX 72           // xA row stride (bf16 elems)

typedef __attribute__((ext_vector_type(8))) short short8;
typedef __attribute__((ext_vector_type(4))) short sshort4;
typedef __attribute__((ext_vector_type(4))) float float4v;

#define MFMA __builtin_amdgcn_mfma_f32_16x16x32_bf16

// single-instruction transcendentals: v_exp_f32 is exp2, v_rcp_f32
__device__ __forceinline__ float sigmoid_f(float x) {
    return __builtin_amdgcn_rcpf(1.0f + __builtin_amdgcn_exp2f(-1.44269504f * x));
}
__device__ __forceinline__ float tanh_fast(float x) {
    // tanh(x) = 1 - 2/(1+e^{2x}); exp2(+-inf) saturates correctly -> no clamp
    return 1.0f - 2.0f * __builtin_amdgcn_rcpf(1.0f + __builtin_amdgcn_exp2f(2.88539008f * x));
}
__device__ __forceinline__ unsigned f2bf_bits(float x) {
    unsigned u = __float_as_uint(x);
    return (u + 0x7fffu + ((u >> 16) & 1u)) >> 16;
}
__device__ __forceinline__ short f2bf(float x) { return (short)f2bf_bits(x); }

// ---------------------------------------------------------------------------
// prep: (a) Bfrag   = gru2d weights, fragment-major bf16 (layout verified R2)
//       (b) Bfrag1  = gru1d Whh, same pack (8 kt)
//       (c) Bfrag1W = gru1d Wih (768 x 912), same pack, K zero-padded to 928
//       (d) fc1Wt transpose
// Fragment layout: [kt][ntile(48)][lane(64)][j(8)] bf16; value = W[n][k] with
// n = ntile*16 + (lane&15), k = kt*32 + (lane>>4)*8 + j.
// ---------------------------------------------------------------------------
__global__ __launch_bounds__(256) void prep_kernel(
        const float* __restrict__ Whh2, const float* __restrict__ Wih2,
        const float* __restrict__ Whh1, const float* __restrict__ Wih1,
        const float* __restrict__ fc1W,
        short* __restrict__ Bfrag, short* __restrict__ Bfrag1,
        short* __restrict__ Bfrag1W, float* __restrict__ fc1Wt) {
    int idx = blockIdx.x * 256 + threadIdx.x;
    if (idx < 10 * 48 * 64 * 8) {
        int j = idx & 7, lane = (idx >> 3) & 63, tile = idx >> 9;
        int nt = tile % 48, kt = tile / 48;
        int n = nt * 16 + (lane & 15);
        int kb = (lane >> 4) * 8 + j;
        float v = (kt < 8) ? Whh2[n * 256 + kt * 32 + kb]
                           : Wih2[n * 64 + (kt - 8) * 32 + kb];
        Bfrag[idx] = f2bf(v);
    }
    if (idx < 8 * 48 * 64 * 8) {
        int j = idx & 7, lane = (idx >> 3) & 63, tile = idx >> 9;
        int nt = tile % 48, kt = tile / 48;
        int n = nt * 16 + (lane & 15);
        int k = kt * 32 + (lane >> 4) * 8 + j;
        Bfrag1[idx] = f2bf(Whh1[n * 256 + k]);
    }
    if (idx < 29 * 48 * 64 * 8) {
        int j = idx & 7, lane = (idx >> 3) & 63, tile = idx >> 9;
        int nt = tile % 48, kt = tile / 48;
        int n = nt * 16 + (lane & 15);
        int k = kt * 32 + (lane >> 4) * 8 + j;
        Bfrag1W[idx] = (k < INTER_) ? f2bf(Wih1[n * INTER_ + k]) : (short)0;
    }
    if (idx < FCIN_ * 256) {
        int o = idx & 255, i = idx >> 8;
        fc1Wt[idx] = fc1W[o * FCIN_ + i];
    }
}

// ---------------------------------------------------------------------------
// reduce_states: d[] reductions + x1 copy -> f[:, 0:400]
// ---------------------------------------------------------------------------
__global__ __launch_bounds__(256) void reduce_states_kernel(
        const float* __restrict__ states, const float* __restrict__ x1,
        float* __restrict__ f) {
    const int c = threadIdx.x & 63;
    const int bj = blockIdx.x * 4 + (threadIdx.x >> 6);
    const int b = bj >> 6, j = bj & 63;
    const float* p1 = states + b * 262144 + j * 64 + c;
    const float* p2 = states + b * 262144 + j * 4096 + c;
    float mx1 = -1e30f, mn1 = 1e30f, sm1 = 0.f;
    float mx2 = -1e30f, mn2 = 1e30f, sm2 = 0.f;
    #pragma unroll 8
    for (int n = 0; n < 64; ++n) {
        float v = p1[n * 4096];
        mx1 = fmaxf(mx1, v); mn1 = fminf(mn1, v); sm1 += v;
    }
    #pragma unroll 8
    for (int m = 0; m < 64; ++m) {
        float v = p2[m * 64];
        mx2 = fmaxf(mx2, v); mn2 = fminf(mn2, v); sm2 += v;
    }
    float* fr = f + bj * INTER_;
    fr[16 + c]  = mx1;  fr[80 + c]  = sm1 * (1.f / 64.f);  fr[144 + c] = mn1;
    fr[208 + c] = mx2;  fr[272 + c] = sm2 * (1.f / 64.f);  fr[336 + c] = mn2;
    if (c < 16) fr[c] = x1[bj * 16 + c];
}

// ---------------------------------------------------------------------------
// gru2d via MFMA bf16, B-resident. R2 (this round):
//  - __launch_bounds__(512, 1): LDS already limits to 1 block/CU; the old
//    ",2" capped VGPRs at 128 and caused massive spill shuffling (44% VALU).
//  - MFMA body: R0-style interleaved 6-chain order (single hA read per kt,
//    all gate accumulators concurrent -> issue-bound, max ILP).
//  - kept from R1: hA double-buffer + single barrier/step, bias-folded
//    accumulator init, exp2/rcp transcendentals.
// ---------------------------------------------------------------------------
__global__ __launch_bounds__(512, 1) void gru2d_mfma(
        const float* __restrict__ states,
        const int* __restrict__ perm1, const int* __restrict__ perm2,
        const short* __restrict__ Bfrag,
        const float* __restrict__ bih, const float* __restrict__ bhh,
        float* __restrict__ f) {
    __shared__ short hA[2][16 * PADA];
    __shared__ short xA[2][16 * PADX];
    __shared__ short8 Blds[2 * 48 * 64];
    __shared__ int perms[1024];

    const int tid = threadIdx.x;
    const int lane = tid & 63;
    const int w = tid >> 6;
    const int m = lane & 15;
    const int q = lane >> 4;
    const bool sd2 = blockIdx.x >= 128;
    const int sblock = (blockIdx.x & 127) * 16;

    for (int i = tid; i < 1024; i += 512) {
        int r = i >> 6, t = i & 63;
        int qq = (sblock + r) & 63;
        perms[i] = sd2 ? perm2[qq * 64 + t] : perm1[qq * 64 + t];
    }
    for (int i = tid; i < 16 * PADA; i += 512) hA[0][i] = 0;
    {
        const uint4* src = (const uint4*)(Bfrag + 6 * 48 * 64 * 8);
        uint4* dst = (uint4*)Blds;
        #pragma unroll
        for (int rep = 0; rep < 12; ++rep)
            dst[tid + rep * 512] = src[tid + rep * 512];
    }

    const short8* Bf8 = (const short8*)Bfrag;
    short8 Bres[36];
    #pragma unroll
    for (int kt = 0; kt < 6; ++kt)
        #pragma unroll
        for (int j = 0; j < 6; ++j)
            Bres[kt * 6 + j] = Bf8[(kt * 48 + 8 * j + w) * 64 + lane];

    const int u0 = 16 * w + m;
    const int u1 = 128 + u0;
    const float br0 = bih[u0] + bhh[u0],             br1 = bih[u1] + bhh[u1];
    const float bz0 = bih[256 + u0] + bhh[256 + u0], bz1 = bih[256 + u1] + bhh[256 + u1];
    const float bnx0 = bih[512 + u0], bnx1 = bih[512 + u1];
    const float bnh0 = bhh[512 + u0], bnh1 = bhh[512 + u1];

    float4v hreg0 = {0.f, 0.f, 0.f, 0.f}, hreg1 = {0.f, 0.f, 0.f, 0.f};

    {
        #pragma unroll
        for (int half = 0; half < 2; ++half) {
            int i = tid + half * 512;
            int r = i >> 6, c = i & 63;
            int s = sblock + r, b = s >> 6, qq = s & 63;
            int p = perms[r * 64 + 0];
            int src = sd2 ? ((b * 64 + p) * 64 + qq) * 64 + c
                          : ((b * 64 + qq) * 64 + p) * 64 + c;
            xA[0][r * PADX + c] = f2bf(states[src]);
        }
    }
    __syncthreads();

    for (int t = 0; t < 64; ++t) {
        const short* hAc = hA[t & 1];
        const short* xAc = xA[t & 1];

        // x-part B fragments: per-step reload from L2-hot Bfrag (keeps the
        // persistent register set = Bres(144) + accs within the 256 budget)
        short8 Bx[12];
        #pragma unroll
        for (int kt = 0; kt < 2; ++kt)
            #pragma unroll
            for (int j = 0; j < 6; ++j)
                Bx[kt * 6 + j] = Bf8[((8 + kt) * 48 + 8 * j + w) * 64 + lane];

        float xg0 = 0.f, xg1 = 0.f;
        int w0 = -1, w1 = -1;
        if (t + 1 < 64) {
            #pragma unroll
            for (int half = 0; half < 2; ++half) {
                int i = tid + half * 512;
                int r = i >> 6, c = i & 63;
                int s = sblock + r, b = s >> 6, qq = s & 63;
                int p = perms[r * 64 + t + 1];
                int src = sd2 ? ((b * 64 + p) * 64 + qq) * 64 + c
                              : ((b * 64 + qq) * 64 + p) * 64 + c;
                float v = states[src];
                if (half == 0) { xg0 = v; w0 = r * PADX + c; }
                else           { xg1 = v; w1 = r * PADX + c; }
            }
        }

        // ---- interleaved 6-chain MFMA (R0 schedule), biases pre-folded ----
        float4v aR0 = {br0, br0, br0, br0},     aR1 = {br1, br1, br1, br1};
        float4v aZ0 = {bz0, bz0, bz0, bz0},     aZ1 = {bz1, bz1, bz1, bz1};
        float4v aNh0 = {bnh0, bnh0, bnh0, bnh0}, aNh1 = {bnh1, bnh1, bnh1, bnh1};
        float4v aNx0 = {bnx0, bnx0, bnx0, bnx0}, aNx1 = {bnx1, bnx1, bnx1, bnx1};

        #pragma unroll
        for (int kt = 0; kt < 6; ++kt) {
            short8 a = *(const short8*)(hAc + m * PADA + kt * 32 + q * 8);
            aR0  = MFMA(a, Bres[kt * 6 + 0], aR0, 0, 0, 0);
            aR1  = MFMA(a, Bres[kt * 6 + 1], aR1, 0, 0, 0);
            aZ0  = MFMA(a, Bres[kt * 6 + 2], aZ0, 0, 0, 0);
            aZ1  = MFMA(a, Bres[kt * 6 + 3], aZ1, 0, 0, 0);
            aNh0 = MFMA(a, Bres[kt * 6 + 4], aNh0, 0, 0, 0);
            aNh1 = MFMA(a, Bres[kt * 6 + 5], aNh1, 0, 0, 0);
        }
        #pragma unroll
        for (int kt = 0; kt < 2; ++kt) {
            short8 a = *(const short8*)(hAc + m * PADA + (6 + kt) * 32 + q * 8);
            short8 b0 = Blds[(kt * 48 + 8 * 0 + w) * 64 + lane];
            short8 b1 = Blds[(kt * 48 + 8 * 1 + w) * 64 + lane];
            short8 b2 = Blds[(kt * 48 + 8 * 2 + w) * 64 + lane];
            short8 b3 = Blds[(kt * 48 + 8 * 3 + w) * 64 + lane];
            short8 b4 = Blds[(kt * 48 + 8 * 4 + w) * 64 + lane];
            short8 b5 = Blds[(kt * 48 + 8 * 5 + w) * 64 + lane];
            aR0  = MFMA(a, b0, aR0, 0, 0, 0);
            aR1  = MFMA(a, b1, aR1, 0, 0, 0);
            aZ0  = MFMA(a, b2, aZ0, 0, 0, 0);
            aZ1  = MFMA(a, b3, aZ1, 0, 0, 0);
            aNh0 = MFMA(a, b4, aNh0, 0, 0, 0);
            aNh1 = MFMA(a, b5, aNh1, 0, 0, 0);
        }
        #pragma unroll
        for (int kt = 0; kt < 2; ++kt) {
            short8 a = *(const short8*)(xAc + m * PADX + kt * 32 + q * 8);
            aR0  = MFMA(a, Bx[kt * 6 + 0], aR0, 0, 0, 0);
            aR1  = MFMA(a, Bx[kt * 6 + 1], aR1, 0, 0, 0);
            aZ0  = MFMA(a, Bx[kt * 6 + 2], aZ0, 0, 0, 0);
            aZ1  = MFMA(a, Bx[kt * 6 + 3], aZ1, 0, 0, 0);
            aNx0 = MFMA(a, Bx[kt * 6 + 4], aNx0, 0, 0, 0);
            aNx1 = MFMA(a, Bx[kt * 6 + 5], aNx1, 0, 0, 0);
        }

        short* hAn = hA[(t + 1) & 1];
        #pragma unroll
        for (int p = 0; p < 4; ++p) {
            int row = q * 4 + p;
            float r0 = sigmoid_f(aR0[p]);
            float z0 = sigmoid_f(aZ0[p]);
            float n0 = tanh_fast(aNx0[p] + r0 * aNh0[p]);
            float h0 = n0 + z0 * (hreg0[p] - n0);
            hreg0[p] = h0;
            hAn[row * PADA + u0] = f2bf(h0);
            float r1 = sigmoid_f(aR1[p]);
            float z1 = sigmoid_f(aZ1[p]);
            float n1 = tanh_fast(aNx1[p] + r1 * aNh1[p]);
            float h1 = n1 + z1 * (hreg1[p] - n1);
            hreg1[p] = h1;
            hAn[row * PADA + u1] = f2bf(h1);
        }
        if (t + 1 < 64) {
            xA[(t + 1) & 1][w0] = f2bf(xg0);
            xA[(t + 1) & 1][w1] = f2bf(xg1);
        }
        __syncthreads();
    }

    const int off = sd2 ? 656 : 400;
    #pragma unroll
    for (int p = 0; p < 4; ++p) {
        int s = sblock + q * 4 + p;
        f[s * INTER_ + off + u0] = hreg0[p];
        f[s * INTER_ + off + u1] = hreg1[p];
    }
}

// ---------------------------------------------------------------------------
// convert f (fp32 [2048][912]) -> fbf (bf16 [2048][928], zero-padded K)
// ---------------------------------------------------------------------------
__global__ __launch_bounds__(256) void convert_f_kernel(
        const float* __restrict__ f, short* __restrict__ fbf) {
    int idx = blockIdx.x * 256 + threadIdx.x;
    int row = idx / 232;
    int c4 = (idx - row * 232) * 4;
    if (row >= 2048) return;
    sshort4 o;
    if (c4 < INTER_) {
        float4v v = *(const float4v*)(f + row * INTER_ + c4);
        o[0] = f2bf(v[0]); o[1] = f2bf(v[1]); o[2] = f2bf(v[2]); o[3] = f2bf(v[3]);
    } else {
        o[0] = 0; o[1] = 0; o[2] = 0; o[3] = 0;
    }
    *(sshort4*)(fbf + row * KP_ + c4) = o;
}

// ---------------------------------------------------------------------------
// xw1[2048][768] = fbf[2048][928] @ Wih1^T (+bih1), bf16 MFMA.
// grid (12 n-blocks, 32 m-blocks) x 256 thr (4 waves); wave w -> rows w*16..+15,
// 4 n-subtiles of 16; reg double-buffered K loop (29 kt), no LDS.
// ---------------------------------------------------------------------------
__global__ __launch_bounds__(256) void gemm_xw1_mfma(
        const short* __restrict__ fbf, const short* __restrict__ BfragW,
        const float* __restrict__ bih, float* __restrict__ xw) {
    const int tid = threadIdx.x;
    const int lane = tid & 63;
    const int w = tid >> 6;
    const int m = lane & 15;
    const int q = lane >> 4;
    const int tn = blockIdx.x;
    const int tm = blockIdx.y;
    const int rowb = tm * 64 + w * 16;
    const short8* Bf8 = (const short8*)BfragW;

    float4v acc[4];
    #pragma unroll
    for (int nn = 0; nn < 4; ++nn) {
        float b = bih[tn * 64 + nn * 16 + m];
        acc[nn][0] = b; acc[nn][1] = b; acc[nn][2] = b; acc[nn][3] = b;
    }

    const short* arow = fbf + (rowb + m) * KP_;
    short8 a_cur = *(const short8*)(arow + q * 8);
    short8 b_cur[4];
    #pragma unroll
    for (int nn = 0; nn < 4; ++nn)
        b_cur[nn] = Bf8[(tn * 4 + nn) * 64 + lane];

    for (int kt = 0; kt < 29; ++kt) {
        short8 a_nxt = a_cur;
        short8 b_nxt[4];
        if (kt + 1 < 29) {
            a_nxt = *(const short8*)(arow + (kt + 1) * 32 + q * 8);
            #pragma unroll
            for (int nn = 0; nn < 4; ++nn)
                b_nxt[nn] = Bf8[((kt + 1) * 48 + tn * 4 + nn) * 64 + lane];
        }
        #pragma unroll
        for (int nn = 0; nn < 4; ++nn)
            acc[nn] = MFMA(a_cur, b_cur[nn], acc[nn], 0, 0, 0);
        a_cur = a_nxt;
        #pragma unroll
        for (int nn = 0; nn < 4; ++nn) b_cur[nn] = b_nxt[nn];
    }

    #pragma unroll
    for (int p = 0; p < 4; ++p) {
        int row = rowb + q * 4 + p;
        #pragma unroll
        for (int nn = 0; nn < 4; ++nn)
            xw[row * G3_ + tn * 64 + nn * 16 + m] = acc[nn][p];
    }
}

// ---------------------------------------------------------------------------
// gru1d via MFMA bf16. R2: __launch_bounds__(512,1) (VGPR 256), interleaved
// 6-chain MFMA order, hA double-buffer + single barrier, bias-folded init.
// ---------------------------------------------------------------------------
__global__ __launch_bounds__(512, 1) void gru1d_mfma(
        const float* __restrict__ xw, const short* __restrict__ Bfrag1,
        const float* __restrict__ bhh, float* __restrict__ hlast) {
    __shared__ short hA[2][16 * PADA];
    __shared__ short8 Blds[2 * 48 * 64];   // kt 6,7

    const int tid = threadIdx.x;
    const int lane = tid & 63;
    const int w = tid >> 6;
    const int m = lane & 15;
    const int q = lane >> 4;
    const int sblock = blockIdx.x * 16;

    for (int i = tid; i < 16 * PADA; i += 512) hA[0][i] = 0;
    {
        const uint4* src = (const uint4*)(Bfrag1 + 6 * 48 * 64 * 8);
        uint4* dst = (uint4*)Blds;
        #pragma unroll
        for (int rep = 0; rep < 12; ++rep)
            dst[tid + rep * 512] = src[tid + rep * 512];
    }
    const short8* Bf8 = (const short8*)Bfrag1;
    short8 Bres[36];
    #pragma unroll
    for (int kt = 0; kt < 6; ++kt)
        #pragma unroll
        for (int j = 0; j < 6; ++j)
            Bres[kt * 6 + j] = Bf8[(kt * 48 + 8 * j + w) * 64 + lane];

    const int u0 = 16 * w + m;
    const int u1 = 128 + u0;
    const float br0 = bhh[u0],       br1 = bhh[u1];
    const float bz0 = bhh[256 + u0], bz1 = bhh[256 + u1];
    const float bn0 = bhh[512 + u0], bn1 = bhh[512 + u1];

    float4v hreg0 = {0.f, 0.f, 0.f, 0.f}, hreg1 = {0.f, 0.f, 0.f, 0.f};
    __syncthreads();

    for (int t = 0; t < 64; ++t) {
        const short* hAc = hA[t & 1];

        // prefetch gi for this step (L2-hot; hides under MFMAs)
        float giR0[4], giR1[4], giZ0[4], giZ1[4], giN0[4], giN1[4];
        #pragma unroll
        for (int p = 0; p < 4; ++p) {
            const float* gr = xw + ((sblock + q * 4 + p) * 64 + t) * G3_;
            giR0[p] = gr[u0];        giR1[p] = gr[u1];
            giZ0[p] = gr[256 + u0];  giZ1[p] = gr[256 + u1];
            giN0[p] = gr[512 + u0];  giN1[p] = gr[512 + u1];
        }

        // ---- interleaved 6-chain MFMA, biases pre-folded ----
        float4v aR0 = {br0, br0, br0, br0}, aR1 = {br1, br1, br1, br1};
        float4v aZ0 = {bz0, bz0, bz0, bz0}, aZ1 = {bz1, bz1, bz1, bz1};
        float4v aN0 = {bn0, bn0, bn0, bn0}, aN1 = {bn1, bn1, bn1, bn1};

        #pragma unroll
        for (int kt = 0; kt < 6; ++kt) {
            short8 a = *(const short8*)(hAc + m * PADA + kt * 32 + q * 8);
            aR0 = MFMA(a, Bres[kt * 6 + 0], aR0, 0, 0, 0);
            aR1 = MFMA(a, Bres[kt * 6 + 1], aR1, 0, 0, 0);
            aZ0 = MFMA(a, Bres[kt * 6 + 2], aZ0, 0, 0, 0);
            aZ1 = MFMA(a, Bres[kt * 6 + 3], aZ1, 0, 0, 0);
            aN0 = MFMA(a, Bres[kt * 6 + 4], aN0, 0, 0, 0);
            aN1 = MFMA(a, Bres[kt * 6 + 5], aN1, 0, 0, 0);
        }
        #pragma unroll
        for (int kt = 0; kt < 2; ++kt) {
            short8 a = *(const short8*)(hAc + m * PADA + (6 + kt) * 32 + q * 8);
            short8 b0 = Blds[(kt * 48 + 8 * 0 + w) * 64 + lane];
            short8 b1 = Blds[(kt * 48 + 8 * 1 + w) * 64 + lane];
            short8 b2 = Blds[(kt * 48 + 8 * 2 + w) * 64 + lane];
            short8 b3 = Blds[(kt * 48 + 8 * 3 + w) * 64 + lane];
            short8 b4 = Blds[(kt * 48 + 8 * 4 + w) * 64 + lane];
            short8 b5 = Blds[(kt * 48 + 8 * 5 + w) * 64 + lane];
            aR0 = MFMA(a, b0, aR0, 0, 0, 0);
            aR1 = MFMA(a, b1, aR1, 0, 0, 0);
            aZ0 = MFMA(a, b2, aZ0, 0, 0, 0);
            aZ1 = MFMA(a, b3, aZ1, 0, 0, 0);
            aN0 = MFMA(a, b4, aN0, 0, 0, 0);
            aN1 = MFMA(a, b5, aN1, 0, 0, 0);
        }

        short* hAn = hA[(t + 1) & 1];
        #pragma unroll
        for (int p = 0; p < 4; ++p) {
            int row = q * 4 + p;
            float r0 = sigmoid_f(giR0[p] + aR0[p]);
            float z0 = sigmoid_f(giZ0[p] + aZ0[p]);
            float n0 = tanh_fast(giN0[p] + r0 * aN0[p]);
            float h0 = n0 + z0 * (hreg0[p] - n0);
            hreg0[p] = h0;
            hAn[row * PADA + u0] = f2bf(h0);
            float r1 = sigmoid_f(giR1[p] + aR1[p]);
            float z1 = sigmoid_f(giZ1[p] + aZ1[p]);
            float n1 = tanh_fast(giN1[p] + r1 * aN1[p]);
            float h1 = n1 + z1 * (hreg1[p] - n1);
            hreg1[p] = h1;
            hAn[row * PADA + u1] = f2bf(h1);
        }
        __syncthreads();
    }

    #pragma unroll
    for (int p = 0; p < 4; ++p) {
        int s = sblock + q * 4 + p;
        hlast[s * 256 + u0] = hreg0[p];
        hlast[s * 256 + u1] = hreg1[p];
    }
}

// ---------------------------------------------------------------------------
// tail: g = [f.max(1)|f.mean(1)|f.min(1)|hlast], fc1+relu, fc2
// ---------------------------------------------------------------------------
__global__ __launch_bounds__(256) void tail_kernel(
        const float* __restrict__ f, const float* __restrict__ hlast,
        const float* __restrict__ fc1Wt, const float* __restrict__ fc1b,
        const float* __restrict__ fc2W, const float* __restrict__ fc2b,
        float* __restrict__ out) {
    __shared__ float g_lds[FCIN_];
    __shared__ float red[256];
    const int tid = threadIdx.x;
    const int b = blockIdx.x;
    for (int i = tid; i < INTER_; i += 256) {
        float mx = -1e30f, mn = 1e30f, sm = 0.f;
        for (int t = 0; t < 64; ++t) {
            float v = f[(b * 64 + t) * INTER_ + i];
            mx = fmaxf(mx, v); mn = fminf(mn, v); sm += v;
        }
        g_lds[i] = mx;
        g_lds[INTER_ + i] = sm * (1.f / 64.f);
        g_lds[2 * INTER_ + i] = mn;
    }
    g_lds[3 * INTER_ + tid] = hlast[b * 256 + tid];
    __syncthreads();
    float acc = fc1b[tid];
    for (int i = 0; i < FCIN_; ++i)
        acc = fmaf(g_lds[i], fc1Wt[i * 256 + tid], acc);
    float hv = fmaxf(acc, 0.f);
    red[tid] = hv * fc2W[tid];
    __syncthreads();
    if (tid == 0) {
        float s = fc2b[0];
        for (int i = 0; i < 256; ++i) s += red[i];
        out[b] = s;
    }
}

// ---------------------------------------------------------------------------
extern "C" void kernel_launch(void* const* d_in, const int* in_sizes, int n_in,
                              void* d_out, int out_size, void* d_ws, size_t ws_size,
                              hipStream_t stream) {
    const float* x1     = (const float*)d_in[0];
    const float* states = (const float*)d_in[1];
    const int*   perm1  = (const int*)d_in[2];
    const int*   perm2  = (const int*)d_in[3];
    const float* Wih2   = (const float*)d_in[4];
    const float* Whh2   = (const float*)d_in[5];
    const float* bih2   = (const float*)d_in[6];
    const float* bhh2   = (const float*)d_in[7];
    const float* Wih1   = (const float*)d_in[8];
    const float* Whh1   = (const float*)d_in[9];
    const float* bih1   = (const float*)d_in[10];
    const float* bhh1   = (const float*)d_in[11];
    const float* fc1W   = (const float*)d_in[12];
    const float* fc1b   = (const float*)d_in[13];
    const float* fc2W   = (const float*)d_in[14];
    const float* fc2b   = (const float*)d_in[15];
    float* out = (float*)d_out;

    float* ws = (float*)d_ws;
    short* Bfrag   = (short*)ws;                          // 245760 bf16
    short* Bfrag1  = (short*)(ws + 122880);               // 196608 bf16
    short* Bfrag1W = (short*)(ws + 122880 + 98304);       // 712704 bf16
    float* fc1Wt   = ws + 577536;                         // 765952 f
    float* f       = fc1Wt + FCIN_ * 256;                 // 1343488
    short* fbf     = (short*)(f + 2048 * INTER_);         // 1900544 bf16
    float* xw1     = f + 2048 * INTER_ + 950272;          // 4161536
    float* hlast   = xw1 + 2048 * G3_;                    // 5734400

    prep_kernel<<<dim3(2992), 256, 0, stream>>>(Whh2, Wih2, Whh1, Wih1, fc1W,
                                                Bfrag, Bfrag1, Bfrag1W, fc1Wt);
    reduce_states_kernel<<<dim3(512), 256, 0, stream>>>(states, x1, f);
    gru2d_mfma<<<dim3(256), 512, 0, stream>>>(states, perm1, perm2, Bfrag,
                                              bih2, bhh2, f);
    convert_f_kernel<<<dim3(1856), 256, 0, stream>>>(f, fbf);
    gemm_xw1_mfma<<<dim3(12, 32), 256, 0, stream>>>(fbf, Bfrag1W, bih1, xw1);
    gru1d_mfma<<<dim3(2), 512, 0, stream>>>(xw1, Bfrag1, bhh1, hlast);
    tail_kernel<<<dim3(32), 256, 0, stream>>>(f, hlast, fc1Wt, fc1b, fc2W, fc2b, out);
}